// Round 5
// baseline (512.868 us; speedup 1.0000x reference)
//
#include <hip/hip_runtime.h>

#define Bsz  4
#define Tseq 2048
#define Cdim 512
#define Hn   8
#define Dh   64
#define BT   8192     // Bsz*Tseq tokens
#define NQKV 1536
#define NEG_BIG (-1e30f)

typedef __attribute__((ext_vector_type(8))) short bf16x8;  // 8 bf16 = 4 VGPRs
typedef __attribute__((ext_vector_type(4))) short bf16x4;  // 4 bf16 = 2 VGPRs
typedef __attribute__((ext_vector_type(4))) float f32x4;

__device__ __forceinline__ float b2f(short s) {
    unsigned u = ((unsigned)(unsigned short)s) << 16;
    float f; __builtin_memcpy(&f, &u, 4); return f;
}
__device__ __forceinline__ short f2b(float f) {
    unsigned u; __builtin_memcpy(&u, &f, 4);
    u = (u + 0x7fffu + ((u >> 16) & 1u)) >> 16;   // RNE
    return (short)u;
}

// ---------------- weight transpose + bf16 cast: W[c][n] (fp32) -> Wt[n][c] (bf16) ----------------
__global__ __launch_bounds__(256) void k_transpose(const float* __restrict__ wq, const float* __restrict__ wk,
                                                   const float* __restrict__ wv, const float* __restrict__ wff,
                                                   short* __restrict__ wqkvt, short* __restrict__ wfft) {
    int idx = blockIdx.x * 256 + threadIdx.x;     // grid covers 1536*512 + 512*512 = 1048576 exactly
    if (idx < NQKV * Cdim) {
        int n = idx >> 9, c = idx & 511;
        int proj = n >> 9, nn = n & 511;
        int h = nn >> 6, d = nn & 63;
        const float* w = (proj == 0) ? wq : (proj == 1 ? wk : wv);
        wqkvt[idx] = f2b(w[(h * Cdim + c) * Dh + d]);
    } else {
        int i2 = idx - NQKV * Cdim;
        int n = i2 >> 9, c = i2 & 511;
        wfft[i2] = f2b(wff[c * Cdim + n]);
    }
}

// ---------------- LayerNorm: fp32 in, bf16 out ----------------
__global__ __launch_bounds__(256) void k_ln(const float* __restrict__ x, const float* __restrict__ g,
                                            const float* __restrict__ b, short* __restrict__ out) {
    int row  = blockIdx.x * 4 + (threadIdx.x >> 6);   // one wave per token row
    int lane = threadIdx.x & 63;
    const f32x4 a0 = *(const f32x4*)(x + row * Cdim + lane * 8);
    const f32x4 a1 = *(const f32x4*)(x + row * Cdim + lane * 8 + 4);
    float v[8] = {a0[0], a0[1], a0[2], a0[3], a1[0], a1[1], a1[2], a1[3]};
    float s = 0.f, sq = 0.f;
#pragma unroll
    for (int i = 0; i < 8; i++) { s += v[i]; sq += v[i] * v[i]; }
#pragma unroll
    for (int off = 1; off < 64; off <<= 1) { s += __shfl_xor(s, off); sq += __shfl_xor(sq, off); }
    float mean = s * (1.f / 512.f);
    float var  = sq * (1.f / 512.f) - mean * mean;
    float rstd = rsqrtf(var + 1e-5f);
    const f32x4 g0 = *(const f32x4*)(g + lane * 8);
    const f32x4 g1 = *(const f32x4*)(g + lane * 8 + 4);
    const f32x4 b0 = *(const f32x4*)(b + lane * 8);
    const f32x4 b1 = *(const f32x4*)(b + lane * 8 + 4);
    float gg[8] = {g0[0], g0[1], g0[2], g0[3], g1[0], g1[1], g1[2], g1[3]};
    float bb[8] = {b0[0], b0[1], b0[2], b0[3], b1[0], b1[1], b1[2], b1[3]};
    bf16x8 o;
#pragma unroll
    for (int i = 0; i < 8; i++) o[i] = f2b((v[i] - mean) * rstd * gg[i] + bb[i]);
    *(bf16x8*)(out + row * Cdim + lane * 8) = o;
}

// ---------------- QKV GEMM: [8192,512] x Wt[1536,512], all bf16 ----------------
__global__ __launch_bounds__(256) void k_gemm_qkv(const short* __restrict__ A, const short* __restrict__ Wt,
                                                  short* __restrict__ q, short* __restrict__ k,
                                                  short* __restrict__ vt) {
    const int wave = threadIdx.x >> 6, lane = threadIdx.x & 63;
    const int quad = lane >> 4, l15 = lane & 15;
    const int m0 = blockIdx.x * 256 + wave * 64;
    const int n0 = blockIdx.y * 64;
    f32x4 acc[4][4];
#pragma unroll
    for (int i = 0; i < 4; i++)
#pragma unroll
        for (int j = 0; j < 4; j++) acc[i][j] = (f32x4){0.f, 0.f, 0.f, 0.f};
    const short* Ab = A  + (m0 + l15) * Cdim + quad * 8;
    const short* Bb = Wt + (n0 + l15) * Cdim + quad * 8;
#pragma unroll 2
    for (int ks = 0; ks < 16; ks++) {
        bf16x8 a[4], w[4];
#pragma unroll
        for (int mt = 0; mt < 4; mt++) a[mt] = *(const bf16x8*)(Ab + mt * 16 * Cdim + ks * 32);
#pragma unroll
        for (int nt = 0; nt < 4; nt++) w[nt] = *(const bf16x8*)(Bb + nt * 16 * Cdim + ks * 32);
#pragma unroll
        for (int mt = 0; mt < 4; mt++)
#pragma unroll
            for (int nt = 0; nt < 4; nt++)
                acc[mt][nt] = __builtin_amdgcn_mfma_f32_16x16x32_bf16(a[mt], w[nt], acc[mt][nt], 0, 0, 0);
    }
    // epilogue: whole block lies in one projection + one head (n-tile = 64 = head size)
    const int proj = n0 >> 9;
    const int hh   = (n0 & 511) >> 6;
#pragma unroll
    for (int mt = 0; mt < 4; mt++) {
#pragma unroll
        for (int r = 0; r < 4; r++) {
            int t  = m0 + mt * 16 + quad * 4 + r;
            int bi = t >> 11, tt = t & 2047;
#pragma unroll
            for (int nt = 0; nt < 4; nt++) {
                int d = nt * 16 + l15;
                short val = f2b(acc[mt][nt][r]);
                if (proj == 0)      q [((bi * Hn + hh) * Tseq + tt) * Dh + d] = val;
                else if (proj == 1) k [((bi * Hn + hh) * Tseq + tt) * Dh + d] = val;
                else                vt[((bi * Hn + hh) * Dh + d) * Tseq + tt] = val;
            }
        }
    }
}

// ---------------- causal flash attention, v3: transposed-score, LDS-free ----------------
// S^T = mfma(K_frag, Q_frag): C-layout lane holds (s=quad*4+r, q=l15). The 4-per-quad
// C-layout IS the A-operand layout of 16x16x16 MFMA (k=quad*4+j), so P feeds the PV
// MFMA directly from registers -- no LDS transpose, no waitcnt fence, loads can pipeline.
// Softmax: per-lane scalar m/l (q=l15); reductions = 15 in-lane ops + 2 shuffles.
__global__ __launch_bounds__(256) void k_attn(const short* __restrict__ qb, const short* __restrict__ kb,
                                              const short* __restrict__ vtb, const float* __restrict__ x,
                                              float* __restrict__ out1) {
    const int wave = threadIdx.x >> 6, lane = threadIdx.x & 63;
    const int quad = lane >> 4, l15 = lane & 15;
    const int bh = blockIdx.y;
    const int qtile = 127 - (blockIdx.x * 4 + wave);   // 0..127, heavy-first
    const int q0 = qtile * 16;
    const short* Q = qb  + bh * Tseq * Dh;
    const short* K = kb  + bh * Tseq * Dh;
    const short* V = vtb + bh * Dh * Tseq;      // [d][s]

    bf16x8 qfr[2];                              // B-operand: lane n=l15 (q), k=quad*8+j (d)
#pragma unroll
    for (int c = 0; c < 2; c++)
        qfr[c] = *(const bf16x8*)(Q + (q0 + l15) * Dh + c * 32 + quad * 8);

    f32x4 o[4];                                 // O tile: row q=quad*4+r, col d=dt*16+l15
#pragma unroll
    for (int i = 0; i < 4; i++) o[i] = (f32x4){0.f, 0.f, 0.f, 0.f};
    float m_i = NEG_BIG, l_i = 0.f;             // per-lane: q = q0 + l15

    const float sc = 0.125f * 1.44269504089f;   // scale * log2(e): softmax in exp2 domain
    const int nkt = (q0 + 79) >> 6;             // 64-key tiles covering keys <= q0+15
    for (int kt = 0; kt < nkt; kt++) {
        const int s0 = kt * 64;
        // S^T tiles: 4 x (16s x 16q); A-frag from K rows (m=s), B-frag = Q
        f32x4 st[4];
#pragma unroll
        for (int nt = 0; nt < 4; nt++) {
            bf16x8 k0 = *(const bf16x8*)(K + (s0 + nt * 16 + l15) * Dh + quad * 8);
            bf16x8 k1 = *(const bf16x8*)(K + (s0 + nt * 16 + l15) * Dh + 32 + quad * 8);
            f32x4 z = (f32x4){0.f, 0.f, 0.f, 0.f};
            z = __builtin_amdgcn_mfma_f32_16x16x32_bf16(k0, qfr[0], z, 0, 0, 0);
            z = __builtin_amdgcn_mfma_f32_16x16x32_bf16(k1, qfr[1], z, 0, 0, 0);
            st[nt] = z;
        }
        const int qq = q0 + l15;                // this lane's q row
        if (s0 + 63 > q0) {                     // causal-boundary tile(s): mask s > q
#pragma unroll
            for (int nt = 0; nt < 4; nt++)
#pragma unroll
                for (int r = 0; r < 4; r++) {
                    int s = s0 + nt * 16 + quad * 4 + r;
                    st[nt][r] = (s > qq) ? NEG_BIG : st[nt][r] * sc;
                }
        } else {
#pragma unroll
            for (int nt = 0; nt < 4; nt++)
#pragma unroll
                for (int r = 0; r < 4; r++) st[nt][r] *= sc;
        }
        // online softmax for q=l15: in-lane 16-way + cross-quad (xor 16,32)
        float mx = st[0][0];
#pragma unroll
        for (int nt = 0; nt < 4; nt++)
#pragma unroll
            for (int r = 0; r < 4; r++) mx = fmaxf(mx, st[nt][r]);
        mx = fmaxf(mx, __shfl_xor(mx, 16));
        mx = fmaxf(mx, __shfl_xor(mx, 32));
        float mn    = fmaxf(m_i, mx);
        float alpha = __builtin_amdgcn_exp2f(m_i - mn);
        m_i = mn;
        float rs = 0.f;
        bf16x4 pf[4];                           // P A-frags: k = quad*4 + j
#pragma unroll
        for (int nt = 0; nt < 4; nt++) {
#pragma unroll
            for (int r = 0; r < 4; r++) {
                float p = __builtin_amdgcn_exp2f(st[nt][r] - mn);  // masked -> 0
                rs += p;
                pf[nt][r] = f2b(p);
            }
        }
        rs += __shfl_xor(rs, 16);
        rs += __shfl_xor(rs, 32);
        l_i = l_i * alpha + rs;
        // rescale O: alpha lives at lane l15=q; O rows are q=quad*4+r
#pragma unroll
        for (int r = 0; r < 4; r++) {
            float ar = __shfl(alpha, quad * 4 + r);
#pragma unroll
            for (int dt = 0; dt < 4; dt++) o[dt][r] *= ar;
        }
        // PV: 16x16x16 MFMA; B-frag = V[s=s0+nt*16+quad*4+j][d=dt*16+l15] = 8B load from vt[d][s]
#pragma unroll
        for (int nt = 0; nt < 4; nt++)
#pragma unroll
            for (int dt = 0; dt < 4; dt++) {
                bf16x4 vf = *(const bf16x4*)(V + (dt * 16 + l15) * Tseq + s0 + nt * 16 + quad * 4);
                o[dt] = __builtin_amdgcn_mfma_f32_16x16x16bf16_1k(pf[nt], vf, o[dt], 0, 0, 0);
            }
    }
    // epilogue: out1 = x + O/l; l lives at lane l15=q, O rows are q=quad*4+r
    const int bi = bh >> 3, hh = bh & 7;
#pragma unroll
    for (int r = 0; r < 4; r++) {
        float lr = __shfl(l_i, quad * 4 + r);
        float inv = 1.f / lr;
        int t   = q0 + quad * 4 + r;
#pragma unroll
        for (int dt = 0; dt < 4; dt++) {
            int idx = (bi * Tseq + t) * Cdim + hh * Dh + dt * 16 + l15;
            out1[idx] = x[idx] + o[dt][r] * inv;
        }
    }
}

// ---------------- FF GEMM: [8192,512] x Wt[512,512], fused bias+ReLU+residual, fp32 out ----------------
__global__ __launch_bounds__(256) void k_gemm_ff(const short* __restrict__ A, const short* __restrict__ Wt,
                                                 const float* __restrict__ bias, const float* __restrict__ res,
                                                 float* __restrict__ out) {
    const int wave = threadIdx.x >> 6, lane = threadIdx.x & 63;
    const int quad = lane >> 4, l15 = lane & 15;
    const int m0 = blockIdx.x * 256 + wave * 64;
    const int n0 = blockIdx.y * 64;
    f32x4 acc[4][4];
#pragma unroll
    for (int i = 0; i < 4; i++)
#pragma unroll
        for (int j = 0; j < 4; j++) acc[i][j] = (f32x4){0.f, 0.f, 0.f, 0.f};
    const short* Ab = A  + (m0 + l15) * Cdim + quad * 8;
    const short* Bb = Wt + (n0 + l15) * Cdim + quad * 8;
#pragma unroll 2
    for (int ks = 0; ks < 16; ks++) {
        bf16x8 a[4], w[4];
#pragma unroll
        for (int mt = 0; mt < 4; mt++) a[mt] = *(const bf16x8*)(Ab + mt * 16 * Cdim + ks * 32);
#pragma unroll
        for (int nt = 0; nt < 4; nt++) w[nt] = *(const bf16x8*)(Bb + nt * 16 * Cdim + ks * 32);
#pragma unroll
        for (int mt = 0; mt < 4; mt++)
#pragma unroll
            for (int nt = 0; nt < 4; nt++)
                acc[mt][nt] = __builtin_amdgcn_mfma_f32_16x16x32_bf16(a[mt], w[nt], acc[mt][nt], 0, 0, 0);
    }
#pragma unroll
    for (int mt = 0; mt < 4; mt++) {
#pragma unroll
        for (int r = 0; r < 4; r++) {
            int t = m0 + mt * 16 + quad * 4 + r;
#pragma unroll
            for (int nt = 0; nt < 4; nt++) {
                int n = n0 + nt * 16 + l15;
                float fv = acc[mt][nt][r] + bias[n];
                fv = fmaxf(fv, 0.f);
                out[t * Cdim + n] = res[t * Cdim + n] + fv;
            }
        }
    }
}

extern "C" void kernel_launch(void* const* d_in, const int* in_sizes, int n_in,
                              void* d_out, int out_size, void* d_ws, size_t ws_size,
                              hipStream_t stream) {
    const float* x   = (const float*)d_in[0];
    const float* wq  = (const float*)d_in[1];
    const float* wk  = (const float*)d_in[2];
    const float* wv  = (const float*)d_in[3];
    const float* wff = (const float*)d_in[4];
    const float* bff = (const float*)d_in[5];
    const float* g1  = (const float*)d_in[6];
    const float* b1  = (const float*)d_in[7];
    const float* g2  = (const float*)d_in[8];
    const float* b2  = (const float*)d_in[9];

    char* p = (char*)d_ws;                                  // ~50 MB total scratch
    short* wqkvt = (short*)p; p += (size_t)NQKV * Cdim * 2;
    short* wfft  = (short*)p; p += (size_t)Cdim * Cdim * 2;
    short* h1    = (short*)p; p += (size_t)BT * Cdim * 2;   // reused as h2 after attention
    short* qb    = (short*)p; p += (size_t)BT * Cdim * 2;
    short* kb    = (short*)p; p += (size_t)BT * Cdim * 2;
    short* vtb   = (short*)p; p += (size_t)BT * Cdim * 2;
    float* out1  = (float*)p; p += (size_t)BT * Cdim * 4;

    hipLaunchKernelGGL(k_transpose, dim3(4096),   dim3(256), 0, stream, wq, wk, wv, wff, wqkvt, wfft);
    hipLaunchKernelGGL(k_ln,        dim3(2048),   dim3(256), 0, stream, x, g1, b1, h1);
    hipLaunchKernelGGL(k_gemm_qkv,  dim3(32, 24), dim3(256), 0, stream, h1, wqkvt, qb, kb, vtb);
    hipLaunchKernelGGL(k_attn,      dim3(32, 32), dim3(256), 0, stream, qb, kb, vtb, x, out1);
    hipLaunchKernelGGL(k_ln,        dim3(2048),   dim3(256), 0, stream, out1, g2, b2, h1);
    hipLaunchKernelGGL(k_gemm_ff,   dim3(32, 8),  dim3(256), 0, stream, h1, wfft, bff, out1, (float*)d_out);
}

// Round 6
// 410.519 us; speedup vs baseline: 1.2493x; 1.2493x over previous
//
#include <hip/hip_runtime.h>

#define Bsz  4
#define Tseq 2048
#define Cdim 512
#define Hn   8
#define Dh   64
#define BT   8192     // Bsz*Tseq tokens
#define NQKV 1536
#define NEG_BIG (-1e30f)

typedef __attribute__((ext_vector_type(8))) short bf16x8;  // 8 bf16 = 4 VGPRs
typedef __attribute__((ext_vector_type(4))) float f32x4;

__device__ __forceinline__ float b2f(short s) {
    unsigned u = ((unsigned)(unsigned short)s) << 16;
    float f; __builtin_memcpy(&f, &u, 4); return f;
}
__device__ __forceinline__ short f2b(float f) {
    unsigned u; __builtin_memcpy(&u, &f, 4);
    u = (u + 0x7fffu + ((u >> 16) & 1u)) >> 16;   // RNE
    return (short)u;
}

// ---------------- weight transpose + bf16 cast: W[c][n] (fp32) -> Wt[n][c] (bf16) ----------------
__global__ __launch_bounds__(256) void k_transpose(const float* __restrict__ wq, const float* __restrict__ wk,
                                                   const float* __restrict__ wv, const float* __restrict__ wff,
                                                   short* __restrict__ wqkvt, short* __restrict__ wfft) {
    int idx = blockIdx.x * 256 + threadIdx.x;     // grid covers 1536*512 + 512*512 = 1048576 exactly
    if (idx < NQKV * Cdim) {
        int n = idx >> 9, c = idx & 511;
        int proj = n >> 9, nn = n & 511;
        int h = nn >> 6, d = nn & 63;
        const float* w = (proj == 0) ? wq : (proj == 1 ? wk : wv);
        wqkvt[idx] = f2b(w[(h * Cdim + c) * Dh + d]);
    } else {
        int i2 = idx - NQKV * Cdim;
        int n = i2 >> 9, c = i2 & 511;
        wfft[i2] = f2b(wff[c * Cdim + n]);
    }
}

// ---------------- LayerNorm: fp32 in, bf16 out ----------------
__global__ __launch_bounds__(256) void k_ln(const float* __restrict__ x, const float* __restrict__ g,
                                            const float* __restrict__ b, short* __restrict__ out) {
    int row  = blockIdx.x * 4 + (threadIdx.x >> 6);   // one wave per token row
    int lane = threadIdx.x & 63;
    const f32x4 a0 = *(const f32x4*)(x + row * Cdim + lane * 8);
    const f32x4 a1 = *(const f32x4*)(x + row * Cdim + lane * 8 + 4);
    float v[8] = {a0[0], a0[1], a0[2], a0[3], a1[0], a1[1], a1[2], a1[3]};
    float s = 0.f, sq = 0.f;
#pragma unroll
    for (int i = 0; i < 8; i++) { s += v[i]; sq += v[i] * v[i]; }
#pragma unroll
    for (int off = 1; off < 64; off <<= 1) { s += __shfl_xor(s, off); sq += __shfl_xor(sq, off); }
    float mean = s * (1.f / 512.f);
    float var  = sq * (1.f / 512.f) - mean * mean;
    float rstd = rsqrtf(var + 1e-5f);
    const f32x4 g0 = *(const f32x4*)(g + lane * 8);
    const f32x4 g1 = *(const f32x4*)(g + lane * 8 + 4);
    const f32x4 b0 = *(const f32x4*)(b + lane * 8);
    const f32x4 b1 = *(const f32x4*)(b + lane * 8 + 4);
    float gg[8] = {g0[0], g0[1], g0[2], g0[3], g1[0], g1[1], g1[2], g1[3]};
    float bb[8] = {b0[0], b0[1], b0[2], b0[3], b1[0], b1[1], b1[2], b1[3]};
    bf16x8 o;
#pragma unroll
    for (int i = 0; i < 8; i++) o[i] = f2b((v[i] - mean) * rstd * gg[i] + bb[i]);
    *(bf16x8*)(out + row * Cdim + lane * 8) = o;
}

// ---------------- QKV GEMM: [8192,512] x Wt[1536,512], all bf16 ----------------
__global__ __launch_bounds__(256) void k_gemm_qkv(const short* __restrict__ A, const short* __restrict__ Wt,
                                                  short* __restrict__ q, short* __restrict__ k,
                                                  short* __restrict__ vt) {
    const int wave = threadIdx.x >> 6, lane = threadIdx.x & 63;
    const int quad = lane >> 4, l15 = lane & 15;
    const int m0 = blockIdx.x * 256 + wave * 64;
    const int n0 = blockIdx.y * 64;
    f32x4 acc[4][4];
#pragma unroll
    for (int i = 0; i < 4; i++)
#pragma unroll
        for (int j = 0; j < 4; j++) acc[i][j] = (f32x4){0.f, 0.f, 0.f, 0.f};
    const short* Ab = A  + (m0 + l15) * Cdim + quad * 8;
    const short* Bb = Wt + (n0 + l15) * Cdim + quad * 8;
#pragma unroll 2
    for (int ks = 0; ks < 16; ks++) {
        bf16x8 a[4], w[4];
#pragma unroll
        for (int mt = 0; mt < 4; mt++) a[mt] = *(const bf16x8*)(Ab + mt * 16 * Cdim + ks * 32);
#pragma unroll
        for (int nt = 0; nt < 4; nt++) w[nt] = *(const bf16x8*)(Bb + nt * 16 * Cdim + ks * 32);
#pragma unroll
        for (int mt = 0; mt < 4; mt++)
#pragma unroll
            for (int nt = 0; nt < 4; nt++)
                acc[mt][nt] = __builtin_amdgcn_mfma_f32_16x16x32_bf16(a[mt], w[nt], acc[mt][nt], 0, 0, 0);
    }
    // epilogue: whole block lies in one projection + one head (n-tile = 64 = head size)
    const int proj = n0 >> 9;
    const int hh   = (n0 & 511) >> 6;
#pragma unroll
    for (int mt = 0; mt < 4; mt++) {
#pragma unroll
        for (int r = 0; r < 4; r++) {
            int t  = m0 + mt * 16 + quad * 4 + r;
            int bi = t >> 11, tt = t & 2047;
#pragma unroll
            for (int nt = 0; nt < 4; nt++) {
                int d = nt * 16 + l15;
                short val = f2b(acc[mt][nt][r]);
                if (proj == 0)      q [((bi * Hn + hh) * Tseq + tt) * Dh + d] = val;
                else if (proj == 1) k [((bi * Hn + hh) * Tseq + tt) * Dh + d] = val;
                else                vt[((bi * Hn + hh) * Dh + d) * Tseq + tt] = val;
            }
        }
    }
}

// ---------------- causal flash attention, v4 ----------------
// v2 structure (best: 235us) minus the compiler memory fence. The P LDS round-trip is
// wave-private: DS ops from one wave execute in order in the LDS pipe, and the compiler
// sees the same-address dependence through psh (cannot reorder read before write; it
// inserts the lgkmcnt wait itself). No "memory" clobber -> compiler may hoist next-tile
// K loads and overlap V-load latency (issued right after S MFMAs) with the softmax.
__global__ __launch_bounds__(256) void k_attn(const short* __restrict__ qb, const short* __restrict__ kb,
                                              const short* __restrict__ vtb, const float* __restrict__ x,
                                              float* __restrict__ out1) {
    const int wave = threadIdx.x >> 6, lane = threadIdx.x & 63;
    const int quad = lane >> 4, l15 = lane & 15;
    const int bh = blockIdx.y;
    const int qtile = 127 - (blockIdx.x * 4 + wave);   // 0..127, heavy-first
    const int q0 = qtile * 16;
    const short* Q = qb  + bh * Tseq * Dh;
    const short* K = kb  + bh * Tseq * Dh;
    const short* V = vtb + bh * Dh * Tseq;      // [d][s]

    __shared__ __align__(16) short psh[4][16 * 72];  // per-wave 16x64 P tile, stride 72
    short* pw = psh[wave];

    bf16x8 qa[2];
#pragma unroll
    for (int c = 0; c < 2; c++)
        qa[c] = *(const bf16x8*)(Q + (q0 + l15) * Dh + c * 32 + quad * 8);

    f32x4 o[4];
#pragma unroll
    for (int i = 0; i < 4; i++) o[i] = (f32x4){0.f, 0.f, 0.f, 0.f};
    float m_i[4], l_i[4];
#pragma unroll
    for (int r = 0; r < 4; r++) { m_i[r] = NEG_BIG; l_i[r] = 0.f; }

    const float sc = 0.125f * 1.44269504089f;   // scale * log2(e): softmax in exp2 domain
    const int nkt = (q0 + 79) >> 6;             // 64-key tiles covering keys <= q0+15
    for (int kt = 0; kt < nkt; kt++) {
        const int s0 = kt * 64;
        // S = Q K^T for a 16q x 64s strip
        f32x4 s[4];
#pragma unroll
        for (int nt = 0; nt < 4; nt++) {
            bf16x8 k0 = *(const bf16x8*)(K + (s0 + nt * 16 + l15) * Dh + quad * 8);
            bf16x8 k1 = *(const bf16x8*)(K + (s0 + nt * 16 + l15) * Dh + 32 + quad * 8);
            f32x4 z = (f32x4){0.f, 0.f, 0.f, 0.f};
            z = __builtin_amdgcn_mfma_f32_16x16x32_bf16(qa[0], k0, z, 0, 0, 0);
            z = __builtin_amdgcn_mfma_f32_16x16x32_bf16(qa[1], k1, z, 0, 0, 0);
            s[nt] = z;
        }
        // V loads issued early: ~whole softmax between issue and first PV use
        bf16x8 vb[2][4];
#pragma unroll
        for (int c = 0; c < 2; c++)
#pragma unroll
            for (int v4 = 0; v4 < 4; v4++)
                vb[c][v4] = *(const bf16x8*)(V + (v4 * 16 + l15) * Tseq + s0 + c * 32 + quad * 8);
        if (s0 + 63 > q0) {                     // wave-uniform: only the causal-boundary tile masks
#pragma unroll
            for (int nt = 0; nt < 4; nt++)
#pragma unroll
                for (int r = 0; r < 4; r++) {
                    int row = q0 + quad * 4 + r;
                    int col = s0 + nt * 16 + l15;
                    s[nt][r] = (col > row) ? NEG_BIG : s[nt][r] * sc;
                }
        } else {
#pragma unroll
            for (int nt = 0; nt < 4; nt++)
#pragma unroll
                for (int r = 0; r < 4; r++) s[nt][r] *= sc;
        }
        float rmax[4];
#pragma unroll
        for (int r = 0; r < 4; r++)
            rmax[r] = fmaxf(fmaxf(s[0][r], s[1][r]), fmaxf(s[2][r], s[3][r]));
#pragma unroll
        for (int r = 0; r < 4; r++)
#pragma unroll
            for (int off = 1; off < 16; off <<= 1)
                rmax[r] = fmaxf(rmax[r], __shfl_xor(rmax[r], off));
        float alpha[4], rsum[4];
#pragma unroll
        for (int r = 0; r < 4; r++) {
            float mn = fmaxf(m_i[r], rmax[r]);
            alpha[r] = __builtin_amdgcn_exp2f(m_i[r] - mn);   // finite-finite: never NaN
            m_i[r] = mn;
            rsum[r] = 0.f;
        }
#pragma unroll
        for (int nt = 0; nt < 4; nt++)
#pragma unroll
            for (int r = 0; r < 4; r++) {
                float p = __builtin_amdgcn_exp2f(s[nt][r] - m_i[r]);  // masked -> exp2(-1e30)=0
                s[nt][r] = p;
                rsum[r] += p;
            }
#pragma unroll
        for (int r = 0; r < 4; r++)
#pragma unroll
            for (int off = 1; off < 16; off <<= 1)
                rsum[r] += __shfl_xor(rsum[r], off);
#pragma unroll
        for (int r = 0; r < 4; r++) l_i[r] = l_i[r] * alpha[r] + rsum[r];
#pragma unroll
        for (int v4 = 0; v4 < 4; v4++)
#pragma unroll
            for (int r = 0; r < 4; r++) o[v4][r] *= alpha[r];
        // P: C-layout -> wave-private LDS -> A-layout. Same-wave DS ops are processed
        // in order by the LDS pipe; compiler tracks the psh dependence + lgkmcnt.
#pragma unroll
        for (int nt = 0; nt < 4; nt++)
#pragma unroll
            for (int r = 0; r < 4; r++)
                pw[(quad * 4 + r) * 72 + nt * 16 + l15] = f2b(s[nt][r]);
        bf16x8 pa[2];
#pragma unroll
        for (int c = 0; c < 2; c++)
            pa[c] = *(const bf16x8*)(pw + l15 * 72 + c * 32 + quad * 8);
#pragma unroll
        for (int c = 0; c < 2; c++)
#pragma unroll
            for (int v4 = 0; v4 < 4; v4++)
                o[v4] = __builtin_amdgcn_mfma_f32_16x16x32_bf16(pa[c], vb[c][v4], o[v4], 0, 0, 0);
    }
    // epilogue: out1 = x + O/l  (fp32); l_i >= 1 always (tile 0 has an unmasked col per row)
    const int bi = bh >> 3, hh = bh & 7;
#pragma unroll
    for (int v4 = 0; v4 < 4; v4++)
#pragma unroll
        for (int r = 0; r < 4; r++) {
            int t   = q0 + quad * 4 + r;
            int idx = (bi * Tseq + t) * Cdim + hh * Dh + v4 * 16 + l15;
            out1[idx] = x[idx] + o[v4][r] / l_i[r];
        }
}

// ---------------- FF GEMM: [8192,512] x Wt[512,512], fused bias+ReLU+residual, fp32 out ----------------
__global__ __launch_bounds__(256) void k_gemm_ff(const short* __restrict__ A, const short* __restrict__ Wt,
                                                 const float* __restrict__ bias, const float* __restrict__ res,
                                                 float* __restrict__ out) {
    const int wave = threadIdx.x >> 6, lane = threadIdx.x & 63;
    const int quad = lane >> 4, l15 = lane & 15;
    const int m0 = blockIdx.x * 256 + wave * 64;
    const int n0 = blockIdx.y * 64;
    f32x4 acc[4][4];
#pragma unroll
    for (int i = 0; i < 4; i++)
#pragma unroll
        for (int j = 0; j < 4; j++) acc[i][j] = (f32x4){0.f, 0.f, 0.f, 0.f};
    const short* Ab = A  + (m0 + l15) * Cdim + quad * 8;
    const short* Bb = Wt + (n0 + l15) * Cdim + quad * 8;
#pragma unroll 2
    for (int ks = 0; ks < 16; ks++) {
        bf16x8 a[4], w[4];
#pragma unroll
        for (int mt = 0; mt < 4; mt++) a[mt] = *(const bf16x8*)(Ab + mt * 16 * Cdim + ks * 32);
#pragma unroll
        for (int nt = 0; nt < 4; nt++) w[nt] = *(const bf16x8*)(Bb + nt * 16 * Cdim + ks * 32);
#pragma unroll
        for (int mt = 0; mt < 4; mt++)
#pragma unroll
            for (int nt = 0; nt < 4; nt++)
                acc[mt][nt] = __builtin_amdgcn_mfma_f32_16x16x32_bf16(a[mt], w[nt], acc[mt][nt], 0, 0, 0);
    }
#pragma unroll
    for (int mt = 0; mt < 4; mt++) {
#pragma unroll
        for (int r = 0; r < 4; r++) {
            int t = m0 + mt * 16 + quad * 4 + r;
#pragma unroll
            for (int nt = 0; nt < 4; nt++) {
                int n = n0 + nt * 16 + l15;
                float fv = acc[mt][nt][r] + bias[n];
                fv = fmaxf(fv, 0.f);
                out[t * Cdim + n] = res[t * Cdim + n] + fv;
            }
        }
    }
}

extern "C" void kernel_launch(void* const* d_in, const int* in_sizes, int n_in,
                              void* d_out, int out_size, void* d_ws, size_t ws_size,
                              hipStream_t stream) {
    const float* x   = (const float*)d_in[0];
    const float* wq  = (const float*)d_in[1];
    const float* wk  = (const float*)d_in[2];
    const float* wv  = (const float*)d_in[3];
    const float* wff = (const float*)d_in[4];
    const float* bff = (const float*)d_in[5];
    const float* g1  = (const float*)d_in[6];
    const float* b1  = (const float*)d_in[7];
    const float* g2  = (const float*)d_in[8];
    const float* b2  = (const float*)d_in[9];

    char* p = (char*)d_ws;                                  // ~50 MB total scratch
    short* wqkvt = (short*)p; p += (size_t)NQKV * Cdim * 2;
    short* wfft  = (short*)p; p += (size_t)Cdim * Cdim * 2;
    short* h1    = (short*)p; p += (size_t)BT * Cdim * 2;   // reused as h2 after attention
    short* qb    = (short*)p; p += (size_t)BT * Cdim * 2;
    short* kb    = (short*)p; p += (size_t)BT * Cdim * 2;
    short* vtb   = (short*)p; p += (size_t)BT * Cdim * 2;
    float* out1  = (float*)p; p += (size_t)BT * Cdim * 4;

    hipLaunchKernelGGL(k_transpose, dim3(4096),   dim3(256), 0, stream, wq, wk, wv, wff, wqkvt, wfft);
    hipLaunchKernelGGL(k_ln,        dim3(2048),   dim3(256), 0, stream, x, g1, b1, h1);
    hipLaunchKernelGGL(k_gemm_qkv,  dim3(32, 24), dim3(256), 0, stream, h1, wqkvt, qb, kb, vtb);
    hipLaunchKernelGGL(k_attn,      dim3(32, 32), dim3(256), 0, stream, qb, kb, vtb, x, out1);
    hipLaunchKernelGGL(k_ln,        dim3(2048),   dim3(256), 0, stream, out1, g2, b2, h1);
    hipLaunchKernelGGL(k_gemm_ff,   dim3(32, 8),  dim3(256), 0, stream, h1, wfft, bff, out1, (float*)d_out);
}

// Round 7
// 336.295 us; speedup vs baseline: 1.5251x; 1.2207x over previous
//
#include <hip/hip_runtime.h>

#define Bsz  4
#define Tseq 2048
#define Cdim 512
#define Hn   8
#define Dh   64
#define BT   8192     // Bsz*Tseq tokens
#define NQKV 1536
#define NEG_BIG (-1e30f)

typedef __attribute__((ext_vector_type(8))) short bf16x8;  // 8 bf16 = 4 VGPRs
typedef __attribute__((ext_vector_type(4))) float f32x4;

__device__ __forceinline__ float b2f(short s) {
    unsigned u = ((unsigned)(unsigned short)s) << 16;
    float f; __builtin_memcpy(&f, &u, 4); return f;
}
__device__ __forceinline__ short f2b(float f) {
    unsigned u; __builtin_memcpy(&u, &f, 4);
    u = (u + 0x7fffu + ((u >> 16) & 1u)) >> 16;   // RNE
    return (short)u;
}

// ---------------- weight transpose + bf16 cast: W[c][n] (fp32) -> Wt[n][c] (bf16) ----------------
__global__ __launch_bounds__(256) void k_transpose(const float* __restrict__ wq, const float* __restrict__ wk,
                                                   const float* __restrict__ wv, const float* __restrict__ wff,
                                                   short* __restrict__ wqkvt, short* __restrict__ wfft) {
    int idx = blockIdx.x * 256 + threadIdx.x;     // grid covers 1536*512 + 512*512 = 1048576 exactly
    if (idx < NQKV * Cdim) {
        int n = idx >> 9, c = idx & 511;
        int proj = n >> 9, nn = n & 511;
        int h = nn >> 6, d = nn & 63;
        const float* w = (proj == 0) ? wq : (proj == 1 ? wk : wv);
        wqkvt[idx] = f2b(w[(h * Cdim + c) * Dh + d]);
    } else {
        int i2 = idx - NQKV * Cdim;
        int n = i2 >> 9, c = i2 & 511;
        wfft[i2] = f2b(wff[c * Cdim + n]);
    }
}

// ---------------- LayerNorm: fp32 in, bf16 out ----------------
__global__ __launch_bounds__(256) void k_ln(const float* __restrict__ x, const float* __restrict__ g,
                                            const float* __restrict__ b, short* __restrict__ out) {
    int row  = blockIdx.x * 4 + (threadIdx.x >> 6);   // one wave per token row
    int lane = threadIdx.x & 63;
    const f32x4 a0 = *(const f32x4*)(x + row * Cdim + lane * 8);
    const f32x4 a1 = *(const f32x4*)(x + row * Cdim + lane * 8 + 4);
    float v[8] = {a0[0], a0[1], a0[2], a0[3], a1[0], a1[1], a1[2], a1[3]};
    float s = 0.f, sq = 0.f;
#pragma unroll
    for (int i = 0; i < 8; i++) { s += v[i]; sq += v[i] * v[i]; }
#pragma unroll
    for (int off = 1; off < 64; off <<= 1) { s += __shfl_xor(s, off); sq += __shfl_xor(sq, off); }
    float mean = s * (1.f / 512.f);
    float var  = sq * (1.f / 512.f) - mean * mean;
    float rstd = rsqrtf(var + 1e-5f);
    const f32x4 g0 = *(const f32x4*)(g + lane * 8);
    const f32x4 g1 = *(const f32x4*)(g + lane * 8 + 4);
    const f32x4 b0 = *(const f32x4*)(b + lane * 8);
    const f32x4 b1 = *(const f32x4*)(b + lane * 8 + 4);
    float gg[8] = {g0[0], g0[1], g0[2], g0[3], g1[0], g1[1], g1[2], g1[3]};
    float bb[8] = {b0[0], b0[1], b0[2], b0[3], b1[0], b1[1], b1[2], b1[3]};
    bf16x8 o;
#pragma unroll
    for (int i = 0; i < 8; i++) o[i] = f2b((v[i] - mean) * rstd * gg[i] + bb[i]);
    *(bf16x8*)(out + row * Cdim + lane * 8) = o;
}

// ---------------- QKV GEMM: [8192,512] x Wt[1536,512], all bf16 ----------------
__global__ __launch_bounds__(256) void k_gemm_qkv(const short* __restrict__ A, const short* __restrict__ Wt,
                                                  short* __restrict__ q, short* __restrict__ k,
                                                  short* __restrict__ vt) {
    const int wave = threadIdx.x >> 6, lane = threadIdx.x & 63;
    const int quad = lane >> 4, l15 = lane & 15;
    const int m0 = blockIdx.x * 256 + wave * 64;
    const int n0 = blockIdx.y * 64;
    f32x4 acc[4][4];
#pragma unroll
    for (int i = 0; i < 4; i++)
#pragma unroll
        for (int j = 0; j < 4; j++) acc[i][j] = (f32x4){0.f, 0.f, 0.f, 0.f};
    const short* Ab = A  + (m0 + l15) * Cdim + quad * 8;
    const short* Bb = Wt + (n0 + l15) * Cdim + quad * 8;
#pragma unroll 2
    for (int ks = 0; ks < 16; ks++) {
        bf16x8 a[4], w[4];
#pragma unroll
        for (int mt = 0; mt < 4; mt++) a[mt] = *(const bf16x8*)(Ab + mt * 16 * Cdim + ks * 32);
#pragma unroll
        for (int nt = 0; nt < 4; nt++) w[nt] = *(const bf16x8*)(Bb + nt * 16 * Cdim + ks * 32);
#pragma unroll
        for (int mt = 0; mt < 4; mt++)
#pragma unroll
            for (int nt = 0; nt < 4; nt++)
                acc[mt][nt] = __builtin_amdgcn_mfma_f32_16x16x32_bf16(a[mt], w[nt], acc[mt][nt], 0, 0, 0);
    }
    // epilogue: whole block lies in one projection + one head (n-tile = 64 = head size)
    const int proj = n0 >> 9;
    const int hh   = (n0 & 511) >> 6;
#pragma unroll
    for (int mt = 0; mt < 4; mt++) {
#pragma unroll
        for (int r = 0; r < 4; r++) {
            int t  = m0 + mt * 16 + quad * 4 + r;
            int bi = t >> 11, tt = t & 2047;
#pragma unroll
            for (int nt = 0; nt < 4; nt++) {
                int d = nt * 16 + l15;
                short val = f2b(acc[mt][nt][r]);
                if (proj == 0)      q [((bi * Hn + hh) * Tseq + tt) * Dh + d] = val;
                else if (proj == 1) k [((bi * Hn + hh) * Tseq + tt) * Dh + d] = val;
                else                vt[((bi * Hn + hh) * Dh + d) * Tseq + tt] = val;
            }
        }
    }
}

// ---------------- causal flash attention, v5: split-K within the block ----------------
// One block per (qtile, bh): 4 waves share the 16 q-rows, each takes key tiles
// kt = w, w+4, ... (v2's proven 64-key inner body, incl. the lgkmcnt fence). Grid is
// 4x bigger (4096 blocks -> ~8 resident/CU = 32 waves/CU) and per-wave chains are 4x
// shorter: wave-level overlap hides the softmax/LDS/load latency chain.
// End: flash-combine of the 4 partials (m,l,O) through LDS (overlays P-scratch,
// barrier-separated).
__global__ __launch_bounds__(256) void k_attn(const short* __restrict__ qb, const short* __restrict__ kb,
                                              const short* __restrict__ vtb, const float* __restrict__ x,
                                              float* __restrict__ out1) {
    const int wave = threadIdx.x >> 6, lane = threadIdx.x & 63;
    const int quad = lane >> 4, l15 = lane & 15;
    const int bh = blockIdx.y;
    const int qtile = 127 - blockIdx.x;         // heavy-first (LPT)
    const int q0 = qtile * 16;
    const short* Q = qb  + bh * Tseq * Dh;
    const short* K = kb  + bh * Tseq * Dh;
    const short* V = vtb + bh * Dh * Tseq;      // [d][s]

    // LDS: combine O-zones (16 KB) overlay the per-wave P tiles (9 KB used in-loop);
    // barrier 1 separates the last P use from the first O-zone write.
    __shared__ __align__(16) float ldsO[4][16][64];   // 16384 B
    __shared__ float ldsM[4][16];                     // outside overlay, written pre-barrier
    __shared__ float ldsL[4][16];
    short* pw = (short*)&ldsO[0][0][0] + wave * (16 * 72);  // 16x64 P tile, stride 72

    bf16x8 qa[2];
#pragma unroll
    for (int c = 0; c < 2; c++)
        qa[c] = *(const bf16x8*)(Q + (q0 + l15) * Dh + c * 32 + quad * 8);

    f32x4 o[4];
#pragma unroll
    for (int i = 0; i < 4; i++) o[i] = (f32x4){0.f, 0.f, 0.f, 0.f};
    float m_i[4], l_i[4];
#pragma unroll
    for (int r = 0; r < 4; r++) { m_i[r] = NEG_BIG; l_i[r] = 0.f; }

    const float sc = 0.125f * 1.44269504089f;   // scale * log2(e): softmax in exp2 domain
    const int nkt = (q0 + 79) >> 6;             // 64-key tiles covering keys <= q0+15
    for (int kt = wave; kt < nkt; kt += 4) {    // strided split-K across the 4 waves
        const int s0 = kt * 64;
        f32x4 s[4];
#pragma unroll
        for (int nt = 0; nt < 4; nt++) {
            bf16x8 k0 = *(const bf16x8*)(K + (s0 + nt * 16 + l15) * Dh + quad * 8);
            bf16x8 k1 = *(const bf16x8*)(K + (s0 + nt * 16 + l15) * Dh + 32 + quad * 8);
            f32x4 z = (f32x4){0.f, 0.f, 0.f, 0.f};
            z = __builtin_amdgcn_mfma_f32_16x16x32_bf16(qa[0], k0, z, 0, 0, 0);
            z = __builtin_amdgcn_mfma_f32_16x16x32_bf16(qa[1], k1, z, 0, 0, 0);
            s[nt] = z;
        }
        if (s0 + 63 > q0) {                     // wave-uniform: only the causal-boundary tile masks
#pragma unroll
            for (int nt = 0; nt < 4; nt++)
#pragma unroll
                for (int r = 0; r < 4; r++) {
                    int row = q0 + quad * 4 + r;
                    int col = s0 + nt * 16 + l15;
                    s[nt][r] = (col > row) ? NEG_BIG : s[nt][r] * sc;
                }
        } else {
#pragma unroll
            for (int nt = 0; nt < 4; nt++)
#pragma unroll
                for (int r = 0; r < 4; r++) s[nt][r] *= sc;
        }
        float rmax[4];
#pragma unroll
        for (int r = 0; r < 4; r++)
            rmax[r] = fmaxf(fmaxf(s[0][r], s[1][r]), fmaxf(s[2][r], s[3][r]));
#pragma unroll
        for (int r = 0; r < 4; r++)
#pragma unroll
            for (int off = 1; off < 16; off <<= 1)
                rmax[r] = fmaxf(rmax[r], __shfl_xor(rmax[r], off));
        float alpha[4], rsum[4];
#pragma unroll
        for (int r = 0; r < 4; r++) {
            float mn = fmaxf(m_i[r], rmax[r]);
            alpha[r] = __builtin_amdgcn_exp2f(m_i[r] - mn);   // finite-finite: never NaN
            m_i[r] = mn;
            rsum[r] = 0.f;
        }
#pragma unroll
        for (int nt = 0; nt < 4; nt++)
#pragma unroll
            for (int r = 0; r < 4; r++) {
                float p = __builtin_amdgcn_exp2f(s[nt][r] - m_i[r]);  // masked -> exp2(-1e30)=0
                s[nt][r] = p;
                rsum[r] += p;
            }
#pragma unroll
        for (int r = 0; r < 4; r++)
#pragma unroll
            for (int off = 1; off < 16; off <<= 1)
                rsum[r] += __shfl_xor(rsum[r], off);
#pragma unroll
        for (int r = 0; r < 4; r++) l_i[r] = l_i[r] * alpha[r] + rsum[r];
#pragma unroll
        for (int v4 = 0; v4 < 4; v4++)
#pragma unroll
            for (int r = 0; r < 4; r++) o[v4][r] *= alpha[r];
        // P: C-layout -> wave-private LDS -> A-layout (fence = proven v2 structure)
#pragma unroll
        for (int nt = 0; nt < 4; nt++)
#pragma unroll
            for (int r = 0; r < 4; r++)
                pw[(quad * 4 + r) * 72 + nt * 16 + l15] = f2b(s[nt][r]);
        asm volatile("s_waitcnt lgkmcnt(0)" ::: "memory");
        bf16x8 pa[2];
#pragma unroll
        for (int c = 0; c < 2; c++)
            pa[c] = *(const bf16x8*)(pw + l15 * 72 + c * 32 + quad * 8);
#pragma unroll
        for (int c = 0; c < 2; c++)
#pragma unroll
            for (int v4 = 0; v4 < 4; v4++) {
                bf16x8 vb = *(const bf16x8*)(V + (v4 * 16 + l15) * Tseq + s0 + c * 32 + quad * 8);
                o[v4] = __builtin_amdgcn_mfma_f32_16x16x32_bf16(pa[c], vb, o[v4], 0, 0, 0);
            }
    }
    // ---- flash-combine of the 4 wave partials ----
    if (l15 == 0)
#pragma unroll
        for (int r = 0; r < 4; r++) ldsM[wave][quad * 4 + r] = m_i[r];
    __syncthreads();                            // all loops done; P-scratch dead from here
    float sw[4];
#pragma unroll
    for (int r = 0; r < 4; r++) {
        int row = quad * 4 + r;
        float M = fmaxf(fmaxf(ldsM[0][row], ldsM[1][row]), fmaxf(ldsM[2][row], ldsM[3][row]));
        sw[r] = __builtin_amdgcn_exp2f(m_i[r] - M);          // empty wave: exp2(-1e30-M)=0
        l_i[r] *= sw[r];
    }
    if (l15 == 0)
#pragma unroll
        for (int r = 0; r < 4; r++) ldsL[wave][quad * 4 + r] = l_i[r];
#pragma unroll
    for (int v4 = 0; v4 < 4; v4++)
#pragma unroll
        for (int r = 0; r < 4; r++)
            ldsO[wave][quad * 4 + r][v4 * 16 + l15] = o[v4][r] * sw[r];
    __syncthreads();
    // wave w sums rows 4w..4w+3; lane covers col = lane (coalesced 256B stores)
    const int bi = bh >> 3, hh = bh & 7;
#pragma unroll
    for (int j = 0; j < 4; j++) {
        int row = wave * 4 + j;
        float L  = ldsL[0][row] + ldsL[1][row] + ldsL[2][row] + ldsL[3][row];
        float Of = ldsO[0][row][lane] + ldsO[1][row][lane] + ldsO[2][row][lane] + ldsO[3][row][lane];
        int t   = q0 + row;
        int idx = (bi * Tseq + t) * Cdim + hh * Dh + lane;
        out1[idx] = x[idx] + Of / L;
    }
}

// ---------------- FF GEMM: [8192,512] x Wt[512,512], fused bias+ReLU+residual, fp32 out ----------------
__global__ __launch_bounds__(256) void k_gemm_ff(const short* __restrict__ A, const short* __restrict__ Wt,
                                                 const float* __restrict__ bias, const float* __restrict__ res,
                                                 float* __restrict__ out) {
    const int wave = threadIdx.x >> 6, lane = threadIdx.x & 63;
    const int quad = lane >> 4, l15 = lane & 15;
    const int m0 = blockIdx.x * 256 + wave * 64;
    const int n0 = blockIdx.y * 64;
    f32x4 acc[4][4];
#pragma unroll
    for (int i = 0; i < 4; i++)
#pragma unroll
        for (int j = 0; j < 4; j++) acc[i][j] = (f32x4){0.f, 0.f, 0.f, 0.f};
    const short* Ab = A  + (m0 + l15) * Cdim + quad * 8;
    const short* Bb = Wt + (n0 + l15) * Cdim + quad * 8;
#pragma unroll 2
    for (int ks = 0; ks < 16; ks++) {
        bf16x8 a[4], w[4];
#pragma unroll
        for (int mt = 0; mt < 4; mt++) a[mt] = *(const bf16x8*)(Ab + mt * 16 * Cdim + ks * 32);
#pragma unroll
        for (int nt = 0; nt < 4; nt++) w[nt] = *(const bf16x8*)(Bb + nt * 16 * Cdim + ks * 32);
#pragma unroll
        for (int mt = 0; mt < 4; mt++)
#pragma unroll
            for (int nt = 0; nt < 4; nt++)
                acc[mt][nt] = __builtin_amdgcn_mfma_f32_16x16x32_bf16(a[mt], w[nt], acc[mt][nt], 0, 0, 0);
    }
#pragma unroll
    for (int mt = 0; mt < 4; mt++) {
#pragma unroll
        for (int r = 0; r < 4; r++) {
            int t = m0 + mt * 16 + quad * 4 + r;
#pragma unroll
            for (int nt = 0; nt < 4; nt++) {
                int n = n0 + nt * 16 + l15;
                float fv = acc[mt][nt][r] + bias[n];
                fv = fmaxf(fv, 0.f);
                out[t * Cdim + n] = res[t * Cdim + n] + fv;
            }
        }
    }
}

extern "C" void kernel_launch(void* const* d_in, const int* in_sizes, int n_in,
                              void* d_out, int out_size, void* d_ws, size_t ws_size,
                              hipStream_t stream) {
    const float* x   = (const float*)d_in[0];
    const float* wq  = (const float*)d_in[1];
    const float* wk  = (const float*)d_in[2];
    const float* wv  = (const float*)d_in[3];
    const float* wff = (const float*)d_in[4];
    const float* bff = (const float*)d_in[5];
    const float* g1  = (const float*)d_in[6];
    const float* b1  = (const float*)d_in[7];
    const float* g2  = (const float*)d_in[8];
    const float* b2  = (const float*)d_in[9];

    char* p = (char*)d_ws;                                  // ~50 MB total scratch
    short* wqkvt = (short*)p; p += (size_t)NQKV * Cdim * 2;
    short* wfft  = (short*)p; p += (size_t)Cdim * Cdim * 2;
    short* h1    = (short*)p; p += (size_t)BT * Cdim * 2;   // reused as h2 after attention
    short* qb    = (short*)p; p += (size_t)BT * Cdim * 2;
    short* kb    = (short*)p; p += (size_t)BT * Cdim * 2;
    short* vtb   = (short*)p; p += (size_t)BT * Cdim * 2;
    float* out1  = (float*)p; p += (size_t)BT * Cdim * 4;

    hipLaunchKernelGGL(k_transpose, dim3(4096),    dim3(256), 0, stream, wq, wk, wv, wff, wqkvt, wfft);
    hipLaunchKernelGGL(k_ln,        dim3(2048),    dim3(256), 0, stream, x, g1, b1, h1);
    hipLaunchKernelGGL(k_gemm_qkv,  dim3(32, 24),  dim3(256), 0, stream, h1, wqkvt, qb, kb, vtb);
    hipLaunchKernelGGL(k_attn,      dim3(128, 32), dim3(256), 0, stream, qb, kb, vtb, x, out1);
    hipLaunchKernelGGL(k_ln,        dim3(2048),    dim3(256), 0, stream, out1, g2, b2, h1);
    hipLaunchKernelGGL(k_gemm_ff,   dim3(32, 8),   dim3(256), 0, stream, h1, wfft, bff, out1, (float*)d_out);
}

// Round 8
// 332.128 us; speedup vs baseline: 1.5442x; 1.0125x over previous
//
#include <hip/hip_runtime.h>

#define Bsz  4
#define Tseq 2048
#define Cdim 512
#define Hn   8
#define Dh   64
#define BT   8192     // Bsz*Tseq tokens
#define NQKV 1536
#define NEG_BIG (-1e30f)

typedef __attribute__((ext_vector_type(8))) short bf16x8;  // 8 bf16 = 4 VGPRs
typedef __attribute__((ext_vector_type(4))) short bf16x4;  // 4 bf16 = 2 VGPRs
typedef __attribute__((ext_vector_type(4))) float f32x4;

__device__ __forceinline__ float b2f(short s) {
    unsigned u = ((unsigned)(unsigned short)s) << 16;
    float f; __builtin_memcpy(&f, &u, 4); return f;
}
__device__ __forceinline__ short f2b(float f) {
    unsigned u; __builtin_memcpy(&u, &f, 4);
    u = (u + 0x7fffu + ((u >> 16) & 1u)) >> 16;   // RNE
    return (short)u;
}

// ---------------- weight transpose + bf16 cast: W[c][n] (fp32) -> Wt[n][c] (bf16) ----------------
__global__ __launch_bounds__(256) void k_transpose(const float* __restrict__ wq, const float* __restrict__ wk,
                                                   const float* __restrict__ wv, const float* __restrict__ wff,
                                                   short* __restrict__ wqkvt, short* __restrict__ wfft) {
    int idx = blockIdx.x * 256 + threadIdx.x;     // grid covers 1536*512 + 512*512 = 1048576 exactly
    if (idx < NQKV * Cdim) {
        int n = idx >> 9, c = idx & 511;
        int proj = n >> 9, nn = n & 511;
        int h = nn >> 6, d = nn & 63;
        const float* w = (proj == 0) ? wq : (proj == 1 ? wk : wv);
        wqkvt[idx] = f2b(w[(h * Cdim + c) * Dh + d]);
    } else {
        int i2 = idx - NQKV * Cdim;
        int n = i2 >> 9, c = i2 & 511;
        wfft[i2] = f2b(wff[c * Cdim + n]);
    }
}

// ---------------- LayerNorm: fp32 in, bf16 out ----------------
__global__ __launch_bounds__(256) void k_ln(const float* __restrict__ x, const float* __restrict__ g,
                                            const float* __restrict__ b, short* __restrict__ out) {
    int row  = blockIdx.x * 4 + (threadIdx.x >> 6);   // one wave per token row
    int lane = threadIdx.x & 63;
    const f32x4 a0 = *(const f32x4*)(x + row * Cdim + lane * 8);
    const f32x4 a1 = *(const f32x4*)(x + row * Cdim + lane * 8 + 4);
    float v[8] = {a0[0], a0[1], a0[2], a0[3], a1[0], a1[1], a1[2], a1[3]};
    float s = 0.f, sq = 0.f;
#pragma unroll
    for (int i = 0; i < 8; i++) { s += v[i]; sq += v[i] * v[i]; }
#pragma unroll
    for (int off = 1; off < 64; off <<= 1) { s += __shfl_xor(s, off); sq += __shfl_xor(sq, off); }
    float mean = s * (1.f / 512.f);
    float var  = sq * (1.f / 512.f) - mean * mean;
    float rstd = rsqrtf(var + 1e-5f);
    const f32x4 g0 = *(const f32x4*)(g + lane * 8);
    const f32x4 g1 = *(const f32x4*)(g + lane * 8 + 4);
    const f32x4 b0 = *(const f32x4*)(b + lane * 8);
    const f32x4 b1 = *(const f32x4*)(b + lane * 8 + 4);
    float gg[8] = {g0[0], g0[1], g0[2], g0[3], g1[0], g1[1], g1[2], g1[3]};
    float bb[8] = {b0[0], b0[1], b0[2], b0[3], b1[0], b1[1], b1[2], b1[3]};
    bf16x8 o;
#pragma unroll
    for (int i = 0; i < 8; i++) o[i] = f2b((v[i] - mean) * rstd * gg[i] + bb[i]);
    *(bf16x8*)(out + row * Cdim + lane * 8) = o;
}

// ---------------- QKV GEMM: [8192,512] x Wt[1536,512], all bf16 ----------------
__global__ __launch_bounds__(256) void k_gemm_qkv(const short* __restrict__ A, const short* __restrict__ Wt,
                                                  short* __restrict__ q, short* __restrict__ k,
                                                  short* __restrict__ vt) {
    const int wave = threadIdx.x >> 6, lane = threadIdx.x & 63;
    const int quad = lane >> 4, l15 = lane & 15;
    const int m0 = blockIdx.x * 256 + wave * 64;
    const int n0 = blockIdx.y * 64;
    f32x4 acc[4][4];
#pragma unroll
    for (int i = 0; i < 4; i++)
#pragma unroll
        for (int j = 0; j < 4; j++) acc[i][j] = (f32x4){0.f, 0.f, 0.f, 0.f};
    const short* Ab = A  + (m0 + l15) * Cdim + quad * 8;
    const short* Bb = Wt + (n0 + l15) * Cdim + quad * 8;
#pragma unroll 2
    for (int ks = 0; ks < 16; ks++) {
        bf16x8 a[4], w[4];
#pragma unroll
        for (int mt = 0; mt < 4; mt++) a[mt] = *(const bf16x8*)(Ab + mt * 16 * Cdim + ks * 32);
#pragma unroll
        for (int nt = 0; nt < 4; nt++) w[nt] = *(const bf16x8*)(Bb + nt * 16 * Cdim + ks * 32);
#pragma unroll
        for (int mt = 0; mt < 4; mt++)
#pragma unroll
            for (int nt = 0; nt < 4; nt++)
                acc[mt][nt] = __builtin_amdgcn_mfma_f32_16x16x32_bf16(a[mt], w[nt], acc[mt][nt], 0, 0, 0);
    }
    // epilogue: whole block lies in one projection + one head (n-tile = 64 = head size)
    const int proj = n0 >> 9;
    const int hh   = (n0 & 511) >> 6;
#pragma unroll
    for (int mt = 0; mt < 4; mt++) {
#pragma unroll
        for (int r = 0; r < 4; r++) {
            int t  = m0 + mt * 16 + quad * 4 + r;
            int bi = t >> 11, tt = t & 2047;
#pragma unroll
            for (int nt = 0; nt < 4; nt++) {
                int d = nt * 16 + l15;
                short val = f2b(acc[mt][nt][r]);
                if (proj == 0)      q [((bi * Hn + hh) * Tseq + tt) * Dh + d] = val;
                else if (proj == 1) k [((bi * Hn + hh) * Tseq + tt) * Dh + d] = val;
                else                vt[((bi * Hn + hh) * Dh + d) * Tseq + tt] = val;
            }
        }
    }
}

// ---------------- causal flash attention, v6: split-K + transposed scores ----------------
// Split-K block structure from v5 (WIN). Scores computed transposed:
// S^T = mfma(K_frag, Q_frag) -> lane holds (s=quad*4+r, q=l15). Softmax is per-lane:
// in-lane reduce over 16 s-values + 2 cross-quad shuffles (lanes {l15,+16,+32,+48} are
// exactly the quad set). P^T -> LDS via 4x ds_write_b64 (r=0..3 contiguous), read back
// in A-layout for the K=32 PV MFMA with 16B V loads. Per-tile DS ops: ~50 -> ~14.
__global__ __launch_bounds__(256) void k_attn(const short* __restrict__ qb, const short* __restrict__ kb,
                                              const short* __restrict__ vtb, const float* __restrict__ x,
                                              float* __restrict__ out1) {
    const int wave = threadIdx.x >> 6, lane = threadIdx.x & 63;
    const int quad = lane >> 4, l15 = lane & 15;
    const int bh = blockIdx.y;
    const int qtile = 127 - blockIdx.x;         // heavy-first (LPT)
    const int q0 = qtile * 16;
    const short* Q = qb  + bh * Tseq * Dh;
    const short* K = kb  + bh * Tseq * Dh;
    const short* V = vtb + bh * Dh * Tseq;      // [d][s]

    // LDS: combine O-zones (16 KB) overlay the per-wave P tiles (9 KB used in-loop);
    // barrier 1 separates the last P use from the first O-zone write.
    __shared__ __align__(16) float ldsO[4][16][64];   // 16384 B
    __shared__ float ldsM[4][16];
    __shared__ float ldsL[4][16];
    short* pw = (short*)&ldsO[0][0][0] + wave * (16 * 72);  // 16x64 P tile, stride 72

    bf16x8 qa[2];
#pragma unroll
    for (int c = 0; c < 2; c++)
        qa[c] = *(const bf16x8*)(Q + (q0 + l15) * Dh + c * 32 + quad * 8);

    f32x4 o[4];
#pragma unroll
    for (int i = 0; i < 4; i++) o[i] = (f32x4){0.f, 0.f, 0.f, 0.f};
    float m_i = NEG_BIG, l_i = 0.f;             // per-lane: this lane's q = q0 + l15

    const float sc = 0.125f * 1.44269504089f;   // scale * log2(e): softmax in exp2 domain
    const int nkt = (q0 + 79) >> 6;             // 64-key tiles covering keys <= q0+15
    for (int kt = wave; kt < nkt; kt += 4) {    // strided split-K across the 4 waves
        const int s0 = kt * 64;
        // S^T: 4 tiles of (16s x 16q); lane holds s=s0+nt*16+quad*4+r, q=q0+l15
        f32x4 st[4];
#pragma unroll
        for (int nt = 0; nt < 4; nt++) {
            bf16x8 k0 = *(const bf16x8*)(K + (s0 + nt * 16 + l15) * Dh + quad * 8);
            bf16x8 k1 = *(const bf16x8*)(K + (s0 + nt * 16 + l15) * Dh + 32 + quad * 8);
            f32x4 z = (f32x4){0.f, 0.f, 0.f, 0.f};
            z = __builtin_amdgcn_mfma_f32_16x16x32_bf16(k0, qa[0], z, 0, 0, 0);
            z = __builtin_amdgcn_mfma_f32_16x16x32_bf16(k1, qa[1], z, 0, 0, 0);
            st[nt] = z;
        }
        const int qq = q0 + l15;
        if (s0 + 63 > q0) {                     // wave-uniform: only causal-boundary tiles mask
#pragma unroll
            for (int nt = 0; nt < 4; nt++)
#pragma unroll
                for (int r = 0; r < 4; r++) {
                    int s = s0 + nt * 16 + quad * 4 + r;
                    st[nt][r] = (s > qq) ? NEG_BIG : st[nt][r] * sc;
                }
        } else {
#pragma unroll
            for (int nt = 0; nt < 4; nt++)
#pragma unroll
                for (int r = 0; r < 4; r++) st[nt][r] *= sc;
        }
        // per-lane online softmax (q=l15): in-lane 16-way + cross-quad xor16/xor32.
        // First tile of wave w has s0=64w <= q0 (16/64 alignment) -> mx finite.
        float mx = fmaxf(fmaxf(fmaxf(st[0][0], st[0][1]), fmaxf(st[0][2], st[0][3])),
                         fmaxf(fmaxf(st[1][0], st[1][1]), fmaxf(st[1][2], st[1][3])));
        mx = fmaxf(mx, fmaxf(fmaxf(fmaxf(st[2][0], st[2][1]), fmaxf(st[2][2], st[2][3])),
                             fmaxf(fmaxf(st[3][0], st[3][1]), fmaxf(st[3][2], st[3][3]))));
        mx = fmaxf(mx, __shfl_xor(mx, 16));
        mx = fmaxf(mx, __shfl_xor(mx, 32));
        float mn    = fmaxf(m_i, mx);
        float alpha = __builtin_amdgcn_exp2f(m_i - mn);
        m_i = mn;
        float rs = 0.f;
        bf16x4 pk[4];                           // P^T packed: r=0..3 contiguous per (nt)
#pragma unroll
        for (int nt = 0; nt < 4; nt++) {
#pragma unroll
            for (int r = 0; r < 4; r++) {
                float p = __builtin_amdgcn_exp2f(st[nt][r] - mn);   // masked -> 0
                rs += p;
                pk[nt][r] = f2b(p);
            }
        }
        rs += __shfl_xor(rs, 16);
        rs += __shfl_xor(rs, 32);
        l_i = l_i * alpha + rs;
        // P^T -> LDS: value (s=nt*16+quad*4+r, q=l15) at pw[q*72 + s]; 4x ds_write_b64
#pragma unroll
        for (int nt = 0; nt < 4; nt++)
            *(bf16x4*)(pw + l15 * 72 + nt * 16 + quad * 4) = pk[nt];
        // rescale O: alpha lives at lane l15=q; O rows are q=quad*4+r
#pragma unroll
        for (int r = 0; r < 4; r++) {
            float ar = __shfl(alpha, quad * 4 + r);
#pragma unroll
            for (int dt = 0; dt < 4; dt++) o[dt][r] *= ar;
        }
        asm volatile("s_waitcnt lgkmcnt(0)" ::: "memory");
        bf16x8 pa[2];
#pragma unroll
        for (int c = 0; c < 2; c++)
            pa[c] = *(const bf16x8*)(pw + l15 * 72 + c * 32 + quad * 8);
#pragma unroll
        for (int c = 0; c < 2; c++)
#pragma unroll
            for (int v4 = 0; v4 < 4; v4++) {
                bf16x8 vb = *(const bf16x8*)(V + (v4 * 16 + l15) * Tseq + s0 + c * 32 + quad * 8);
                o[v4] = __builtin_amdgcn_mfma_f32_16x16x32_bf16(pa[c], vb, o[v4], 0, 0, 0);
            }
    }
    // ---- flash-combine of the 4 wave partials (m,l per-lane at q=l15) ----
    if (quad == 0) ldsM[wave][l15] = m_i;
    __syncthreads();                            // all loops done; P-scratch dead from here
    float Ml = fmaxf(fmaxf(ldsM[0][l15], ldsM[1][l15]), fmaxf(ldsM[2][l15], ldsM[3][l15]));
    float swl = __builtin_amdgcn_exp2f(m_i - Ml);            // empty wave: exp2(-1e30-M)=0
    l_i *= swl;
    if (quad == 0) ldsL[wave][l15] = l_i;
#pragma unroll
    for (int r = 0; r < 4; r++) {
        int row = quad * 4 + r;
        float Mr  = fmaxf(fmaxf(ldsM[0][row], ldsM[1][row]), fmaxf(ldsM[2][row], ldsM[3][row]));
        float swr = __builtin_amdgcn_exp2f(ldsM[wave][row] - Mr);
#pragma unroll
        for (int v4 = 0; v4 < 4; v4++)
            ldsO[wave][row][v4 * 16 + l15] = o[v4][r] * swr;
    }
    __syncthreads();
    // wave w sums rows 4w..4w+3; lane covers col = lane (coalesced 256B stores)
    const int bi = bh >> 3, hh = bh & 7;
#pragma unroll
    for (int j = 0; j < 4; j++) {
        int row = wave * 4 + j;
        float L  = ldsL[0][row] + ldsL[1][row] + ldsL[2][row] + ldsL[3][row];
        float Of = ldsO[0][row][lane] + ldsO[1][row][lane] + ldsO[2][row][lane] + ldsO[3][row][lane];
        int t   = q0 + row;
        int idx = (bi * Tseq + t) * Cdim + hh * Dh + lane;
        out1[idx] = x[idx] + Of / L;
    }
}

// ---------------- FF GEMM: [8192,512] x Wt[512,512], fused bias+ReLU+residual, fp32 out ----------------
__global__ __launch_bounds__(256) void k_gemm_ff(const short* __restrict__ A, const short* __restrict__ Wt,
                                                 const float* __restrict__ bias, const float* __restrict__ res,
                                                 float* __restrict__ out) {
    const int wave = threadIdx.x >> 6, lane = threadIdx.x & 63;
    const int quad = lane >> 4, l15 = lane & 15;
    const int m0 = blockIdx.x * 256 + wave * 64;
    const int n0 = blockIdx.y * 64;
    f32x4 acc[4][4];
#pragma unroll
    for (int i = 0; i < 4; i++)
#pragma unroll
        for (int j = 0; j < 4; j++) acc[i][j] = (f32x4){0.f, 0.f, 0.f, 0.f};
    const short* Ab = A  + (m0 + l15) * Cdim + quad * 8;
    const short* Bb = Wt + (n0 + l15) * Cdim + quad * 8;
#pragma unroll 2
    for (int ks = 0; ks < 16; ks++) {
        bf16x8 a[4], w[4];
#pragma unroll
        for (int mt = 0; mt < 4; mt++) a[mt] = *(const bf16x8*)(Ab + mt * 16 * Cdim + ks * 32);
#pragma unroll
        for (int nt = 0; nt < 4; nt++) w[nt] = *(const bf16x8*)(Bb + nt * 16 * Cdim + ks * 32);
#pragma unroll
        for (int mt = 0; mt < 4; mt++)
#pragma unroll
            for (int nt = 0; nt < 4; nt++)
                acc[mt][nt] = __builtin_amdgcn_mfma_f32_16x16x32_bf16(a[mt], w[nt], acc[mt][nt], 0, 0, 0);
    }
#pragma unroll
    for (int mt = 0; mt < 4; mt++) {
#pragma unroll
        for (int r = 0; r < 4; r++) {
            int t = m0 + mt * 16 + quad * 4 + r;
#pragma unroll
            for (int nt = 0; nt < 4; nt++) {
                int n = n0 + nt * 16 + l15;
                float fv = acc[mt][nt][r] + bias[n];
                fv = fmaxf(fv, 0.f);
                out[t * Cdim + n] = res[t * Cdim + n] + fv;
            }
        }
    }
}

extern "C" void kernel_launch(void* const* d_in, const int* in_sizes, int n_in,
                              void* d_out, int out_size, void* d_ws, size_t ws_size,
                              hipStream_t stream) {
    const float* x   = (const float*)d_in[0];
    const float* wq  = (const float*)d_in[1];
    const float* wk  = (const float*)d_in[2];
    const float* wv  = (const float*)d_in[3];
    const float* wff = (const float*)d_in[4];
    const float* bff = (const float*)d_in[5];
    const float* g1  = (const float*)d_in[6];
    const float* b1  = (const float*)d_in[7];
    const float* g2  = (const float*)d_in[8];
    const float* b2  = (const float*)d_in[9];

    char* p = (char*)d_ws;                                  // ~50 MB total scratch
    short* wqkvt = (short*)p; p += (size_t)NQKV * Cdim * 2;
    short* wfft  = (short*)p; p += (size_t)Cdim * Cdim * 2;
    short* h1    = (short*)p; p += (size_t)BT * Cdim * 2;   // reused as h2 after attention
    short* qb    = (short*)p; p += (size_t)BT * Cdim * 2;
    short* kb    = (short*)p; p += (size_t)BT * Cdim * 2;
    short* vtb   = (short*)p; p += (size_t)BT * Cdim * 2;
    float* out1  = (float*)p; p += (size_t)BT * Cdim * 4;

    hipLaunchKernelGGL(k_transpose, dim3(4096),    dim3(256), 0, stream, wq, wk, wv, wff, wqkvt, wfft);
    hipLaunchKernelGGL(k_ln,        dim3(2048),    dim3(256), 0, stream, x, g1, b1, h1);
    hipLaunchKernelGGL(k_gemm_qkv,  dim3(32, 24),  dim3(256), 0, stream, h1, wqkvt, qb, kb, vtb);
    hipLaunchKernelGGL(k_attn,      dim3(128, 32), dim3(256), 0, stream, qb, kb, vtb, x, out1);
    hipLaunchKernelGGL(k_ln,        dim3(2048),    dim3(256), 0, stream, out1, g2, b2, h1);
    hipLaunchKernelGGL(k_gemm_ff,   dim3(32, 8),   dim3(256), 0, stream, h1, wfft, bff, out1, (float*)d_out);
}